// Round 4
// baseline (1779.224 us; speedup 1.0000x reference)
//
#include <hip/hip_runtime.h>

#define BATCH 4096
#define NPATCH 16

// ---------------------------------------------------------------------------
// Kernel 1: per-sample stable rank of noise -> ids_restore (target, as f32)
// and ids_shuffle (inverse permutation) for the gather.
// ---------------------------------------------------------------------------
__global__ void rank_kernel(const float* __restrict__ noise,
                            int* __restrict__ ids_shuffle,
                            float* __restrict__ target_out) {
    int n = blockIdx.x * 256 + threadIdx.x;
    if (n >= BATCH) return;
    float v[NPATCH];
#pragma unroll
    for (int i = 0; i < NPATCH; i++) v[i] = noise[n * NPATCH + i];
#pragma unroll
    for (int j = 0; j < NPATCH; j++) {
        int r = 0;
#pragma unroll
        for (int i = 0; i < NPATCH; i++) {
            if (v[i] < v[j] || (v[i] == v[j] && i < j)) r++;
        }
        ids_shuffle[n * NPATCH + r] = j;
        target_out[n * NPATCH + j] = (float)r;
    }
}

// ---------------------------------------------------------------------------
// Kernel 2: fused patch-shuffle + NCHW -> CHWN transpose.
// y[c][h][w][n] = x[n][c][sh][sw] where (sh,sw) come from patch ids_shuffle.
// Block: 256 threads handles one (c,h) row x 64 n x 32 w via LDS tile.
// ---------------------------------------------------------------------------
__global__ void shuffle_transpose(const float* __restrict__ x,
                                  const int* __restrict__ ids,
                                  float* __restrict__ y) {
    __shared__ float tile[64][33];
    int ch = blockIdx.x;           // c*32 + h, 0..95
    int c = ch >> 5, h = ch & 31;
    int n0 = blockIdx.y << 6;      // 64 n per block
    int t = threadIdx.x;
    int w = t & 31;
    int jrow = (h >> 3) << 2;
#pragma unroll
    for (int r = 0; r < 8; r++) {
        int nl = (t >> 5) + (r << 3);      // 0..63
        int n = n0 + nl;
        int j = jrow + (w >> 3);
        int p = ids[(n << 4) + j];
        int sh = ((p >> 2) << 3) | (h & 7);
        int sw = ((p & 3) << 3) | (w & 7);
        tile[nl][w] = x[n * 3072 + (c << 10) + (sh << 5) + sw];
    }
    __syncthreads();
#pragma unroll
    for (int r = 0; r < 8; r++) {
        int wo = (t >> 6) + (r << 2);      // 0..31
        int nl = t & 63;
        y[((size_t)(ch << 5) + wo) * 4096 + n0 + nl] = tile[nl][wo];
    }
}

// ---------------------------------------------------------------------------
// Kernel 3: conv1 (3->32, 3x3 SAME) + relu + maxpool2, CHWN layout.
// x: [3][32][32][4096], y: [32][16][16][4096].
// Thread: one n, one pooled position; loops all 32 oc with window in regs.
// ---------------------------------------------------------------------------
__global__ void conv1_kernel(const float* __restrict__ x,
                             const float* __restrict__ cw,
                             const float* __restrict__ cb,
                             float* __restrict__ y) {
    int n = (blockIdx.y << 8) + threadIdx.x;
    int pos = blockIdx.x;          // 0..255
    int ph = pos >> 4, pw = pos & 15;
    float win[3][4][4];
#pragma unroll
    for (int ic = 0; ic < 3; ic++)
#pragma unroll
        for (int r = 0; r < 4; r++) {
            int ih = 2 * ph - 1 + r;
#pragma unroll
            for (int cc = 0; cc < 4; cc++) {
                int iw = 2 * pw - 1 + cc;
                bool ok = (ih >= 0) && (ih < 32) && (iw >= 0) && (iw < 32);
                win[ic][r][cc] = ok ? x[((ic * 32 + ih) * 32 + iw) * 4096 + n] : 0.f;
            }
        }
    for (int oc = 0; oc < 32; oc++) {
        float b = cb[oc];
        float a00 = b, a01 = b, a10 = b, a11 = b;
#pragma unroll
        for (int ic = 0; ic < 3; ic++)
#pragma unroll
            for (int kh = 0; kh < 3; kh++)
#pragma unroll
                for (int kw = 0; kw < 3; kw++) {
                    float ww = cw[((oc * 3 + ic) * 3 + kh) * 3 + kw];
                    a00 = fmaf(win[ic][kh][kw],         ww, a00);
                    a01 = fmaf(win[ic][kh][kw + 1],     ww, a01);
                    a10 = fmaf(win[ic][kh + 1][kw],     ww, a10);
                    a11 = fmaf(win[ic][kh + 1][kw + 1], ww, a11);
                }
        float m = fmaxf(fmaxf(a00, a01), fmaxf(a10, a11));
        y[(size_t)(oc * 256 + pos) * 4096 + n] = fmaxf(m, 0.f);
    }
}

// ---------------------------------------------------------------------------
// Kernel 4: conv2 (32->64) + relu + pool. x: [32][16][16][4096],
// y: [64][8][8][4096]. Thread: one n, one pooled pos, 8 oc; stream ic.
// ---------------------------------------------------------------------------
__global__ void conv2_kernel(const float* __restrict__ x,
                             const float* __restrict__ cw,
                             const float* __restrict__ cb,
                             float* __restrict__ y) {
    int n = (blockIdx.y << 8) + threadIdx.x;
    int bid = blockIdx.x;          // 0..511
    int pos = bid & 63, ocg = bid >> 6;
    int ph = pos >> 3, pw = pos & 7;
    float acc[8][4];
#pragma unroll
    for (int o = 0; o < 8; o++) {
        float b = cb[ocg * 8 + o];
        acc[o][0] = acc[o][1] = acc[o][2] = acc[o][3] = b;
    }
    for (int ic = 0; ic < 32; ic++) {
        float win[4][4];
#pragma unroll
        for (int r = 0; r < 4; r++) {
            int ih = 2 * ph - 1 + r;
#pragma unroll
            for (int cc = 0; cc < 4; cc++) {
                int iw = 2 * pw - 1 + cc;
                bool ok = (ih >= 0) && (ih < 16) && (iw >= 0) && (iw < 16);
                win[r][cc] = ok ? x[((ic * 16 + ih) * 16 + iw) * 4096 + n] : 0.f;
            }
        }
#pragma unroll
        for (int o = 0; o < 8; o++) {
            const float* wp = cw + ((ocg * 8 + o) * 32 + ic) * 9;
#pragma unroll
            for (int kh = 0; kh < 3; kh++)
#pragma unroll
                for (int kw = 0; kw < 3; kw++) {
                    float ww = wp[kh * 3 + kw];
                    acc[o][0] = fmaf(win[kh][kw],         ww, acc[o][0]);
                    acc[o][1] = fmaf(win[kh][kw + 1],     ww, acc[o][1]);
                    acc[o][2] = fmaf(win[kh + 1][kw],     ww, acc[o][2]);
                    acc[o][3] = fmaf(win[kh + 1][kw + 1], ww, acc[o][3]);
                }
        }
    }
#pragma unroll
    for (int o = 0; o < 8; o++) {
        float m = fmaxf(fmaxf(acc[o][0], acc[o][1]), fmaxf(acc[o][2], acc[o][3]));
        y[(size_t)((ocg * 8 + o) * 64 + pos) * 4096 + n] = fmaxf(m, 0.f);
    }
}

// ---------------------------------------------------------------------------
// Kernel 5: conv3 (64->128) + relu + pool. x: [64][8][8][4096],
// y: [128][4][4][4096].
// ---------------------------------------------------------------------------
__global__ void conv3_kernel(const float* __restrict__ x,
                             const float* __restrict__ cw,
                             const float* __restrict__ cb,
                             float* __restrict__ y) {
    int n = (blockIdx.y << 8) + threadIdx.x;
    int bid = blockIdx.x;          // 0..255
    int pos = bid & 15, ocg = bid >> 4;
    int ph = pos >> 2, pw = pos & 3;
    float acc[8][4];
#pragma unroll
    for (int o = 0; o < 8; o++) {
        float b = cb[ocg * 8 + o];
        acc[o][0] = acc[o][1] = acc[o][2] = acc[o][3] = b;
    }
    for (int ic = 0; ic < 64; ic++) {
        float win[4][4];
#pragma unroll
        for (int r = 0; r < 4; r++) {
            int ih = 2 * ph - 1 + r;
#pragma unroll
            for (int cc = 0; cc < 4; cc++) {
                int iw = 2 * pw - 1 + cc;
                bool ok = (ih >= 0) && (ih < 8) && (iw >= 0) && (iw < 8);
                win[r][cc] = ok ? x[((ic * 8 + ih) * 8 + iw) * 4096 + n] : 0.f;
            }
        }
#pragma unroll
        for (int o = 0; o < 8; o++) {
            const float* wp = cw + ((ocg * 8 + o) * 64 + ic) * 9;
#pragma unroll
            for (int kh = 0; kh < 3; kh++)
#pragma unroll
                for (int kw = 0; kw < 3; kw++) {
                    float ww = wp[kh * 3 + kw];
                    acc[o][0] = fmaf(win[kh][kw],         ww, acc[o][0]);
                    acc[o][1] = fmaf(win[kh][kw + 1],     ww, acc[o][1]);
                    acc[o][2] = fmaf(win[kh + 1][kw],     ww, acc[o][2]);
                    acc[o][3] = fmaf(win[kh + 1][kw + 1], ww, acc[o][3]);
                }
        }
    }
#pragma unroll
    for (int o = 0; o < 8; o++) {
        float m = fmaxf(fmaxf(acc[o][0], acc[o][1]), fmaxf(acc[o][2], acc[o][3]));
        y[(size_t)((ocg * 8 + o) * 16 + pos) * 4096 + n] = fmaxf(m, 0.f);
    }
}

// ---------------------------------------------------------------------------
// Kernel 6: FC GEMM. C[M,No] = act(A @ W + b). W: [K][No] row-major.
// ATRANS: A stored as [K][M] (fc1 reads conv3's CHWN output directly).
// 64x64 tile, 256 threads, 4x4 microtile, KT=16.
// ---------------------------------------------------------------------------
template <bool ATRANS, bool RELU>
__global__ void fc_kernel(const float* __restrict__ A, const float* __restrict__ W,
                          const float* __restrict__ bias, float* __restrict__ C,
                          int M, int K, int Nout) {
    __shared__ float As[16][68];   // padded: kills 16-way write conflict, 272B rows stay 16B-aligned
    __shared__ float Bs[16][64];
    int tid = threadIdx.x;
    int tile_m = blockIdx.y << 6, tile_n = blockIdx.x << 6;
    int tm = (tid >> 4) << 2;      // 0..60
    int tn = (tid & 15) << 2;      // 0..60
    float acc[4][4] = {};
    for (int k0 = 0; k0 < K; k0 += 16) {
        if (ATRANS) {
#pragma unroll
            for (int pass = 0; pass < 4; pass++) {
                int kk = (tid >> 6) + (pass << 2);
                int r = tid & 63;
                As[kk][r] = A[(size_t)(k0 + kk) * M + tile_m + r];
            }
        } else {
#pragma unroll
            for (int pass = 0; pass < 4; pass++) {
                int r = (tid >> 4) + (pass << 4);
                int kk = tid & 15;
                As[kk][r] = A[(size_t)(tile_m + r) * K + k0 + kk];
            }
        }
#pragma unroll
        for (int pass = 0; pass < 4; pass++) {
            int kk = (tid >> 6) + (pass << 2);
            int o = tid & 63;
            Bs[kk][o] = W[(size_t)(k0 + kk) * Nout + tile_n + o];
        }
        __syncthreads();
#pragma unroll
        for (int kk = 0; kk < 16; kk++) {
            float a0 = As[kk][tm], a1 = As[kk][tm + 1], a2 = As[kk][tm + 2], a3 = As[kk][tm + 3];
            float b0 = Bs[kk][tn], b1 = Bs[kk][tn + 1], b2 = Bs[kk][tn + 2], b3 = Bs[kk][tn + 3];
            acc[0][0] = fmaf(a0, b0, acc[0][0]); acc[0][1] = fmaf(a0, b1, acc[0][1]);
            acc[0][2] = fmaf(a0, b2, acc[0][2]); acc[0][3] = fmaf(a0, b3, acc[0][3]);
            acc[1][0] = fmaf(a1, b0, acc[1][0]); acc[1][1] = fmaf(a1, b1, acc[1][1]);
            acc[1][2] = fmaf(a1, b2, acc[1][2]); acc[1][3] = fmaf(a1, b3, acc[1][3]);
            acc[2][0] = fmaf(a2, b0, acc[2][0]); acc[2][1] = fmaf(a2, b1, acc[2][1]);
            acc[2][2] = fmaf(a2, b2, acc[2][2]); acc[2][3] = fmaf(a2, b3, acc[2][3]);
            acc[3][0] = fmaf(a3, b0, acc[3][0]); acc[3][1] = fmaf(a3, b1, acc[3][1]);
            acc[3][2] = fmaf(a3, b2, acc[3][2]); acc[3][3] = fmaf(a3, b3, acc[3][3]);
        }
        __syncthreads();
    }
#pragma unroll
    for (int i = 0; i < 4; i++) {
        int row = tile_m + tm + i;
#pragma unroll
        for (int j = 0; j < 4; j++) {
            float v = acc[i][j] + bias[tile_n + tn + j];
            if (RELU) v = fmaxf(v, 0.f);
            C[(size_t)row * Nout + tile_n + tn + j] = v;
        }
    }
}

// ---------------------------------------------------------------------------
extern "C" void kernel_launch(void* const* d_in, const int* in_sizes, int n_in,
                              void* d_out, int out_size, void* d_ws, size_t ws_size,
                              hipStream_t stream) {
    const float* x     = (const float*)d_in[0];
    const float* noise = (const float*)d_in[1];
    const float* c1w = (const float*)d_in[2];  const float* c1b = (const float*)d_in[3];
    const float* c2w = (const float*)d_in[4];  const float* c2b = (const float*)d_in[5];
    const float* c3w = (const float*)d_in[6];  const float* c3b = (const float*)d_in[7];
    const float* f1w = (const float*)d_in[8];  const float* f1b = (const float*)d_in[9];
    const float* f2w = (const float*)d_in[10]; const float* f2b = (const float*)d_in[11];
    const float* f3w = (const float*)d_in[12]; const float* f3b = (const float*)d_in[13];
    const float* f4w = (const float*)d_in[14]; const float* f4b = (const float*)d_in[15];
    const float* f5w = (const float*)d_in[16]; const float* f5b = (const float*)d_in[17];
    float* out = (float*)d_out;

    char* ws = (char*)d_ws;
    const size_t MB = 1ull << 20;
    int*   ids  = (int*)ws;                         // 256 KB
    float* bufA = (float*)(ws + 1 * MB);            // 134.2 MB: conv1 out / fc ping
    float* bufB = (float*)(ws + (1 + 136) * MB);    //  67.1 MB: shuffled x / conv2 out / fc pong
    float* bufC = (float*)(ws + (1 + 136 + 68) * MB); // 33.6 MB: conv3 out

    // 1) ranks: ids_shuffle (ws) + ids_restore -> d_out tail (as f32)
    rank_kernel<<<BATCH / 256, 256, 0, stream>>>(noise, ids, out + (size_t)BATCH * 256);
    // 2) patch shuffle + NCHW->CHWN
    shuffle_transpose<<<dim3(96, 64), 256, 0, stream>>>(x, ids, bufB);
    // 3) convs (CHWN)
    conv1_kernel<<<dim3(256, 16), 256, 0, stream>>>(bufB, c1w, c1b, bufA);
    conv2_kernel<<<dim3(512, 16), 256, 0, stream>>>(bufA, c2w, c2b, bufB);
    conv3_kernel<<<dim3(256, 16), 256, 0, stream>>>(bufB, c3w, c3b, bufC);
    // 4) FCs: fc1 reads conv3's [K=2048][M=4096] layout directly (ATRANS)
    fc_kernel<true,  true ><<<dim3(16, 64), 256, 0, stream>>>(bufC, f1w, f1b, bufA, BATCH, 2048, 1024);
    fc_kernel<false, true ><<<dim3(16, 64), 256, 0, stream>>>(bufA, f2w, f2b, bufB, BATCH, 1024, 1024);
    fc_kernel<false, true ><<<dim3(16, 64), 256, 0, stream>>>(bufB, f3w, f3b, bufA, BATCH, 1024, 1024);
    fc_kernel<false, true ><<<dim3(16, 64), 256, 0, stream>>>(bufA, f4w, f4b, bufB, BATCH, 1024, 1024);
    fc_kernel<false, false><<<dim3(4, 64),  256, 0, stream>>>(bufB, f5w, f5b, out, BATCH, 1024, 256);
}

// Round 5
// 534.655 us; speedup vs baseline: 3.3278x; 3.3278x over previous
//
#include <hip/hip_runtime.h>

#define BATCH 4096
#define NPATCH 16

typedef __attribute__((ext_vector_type(8)))  short  short8;
typedef __attribute__((ext_vector_type(4)))  float  f32x4;
typedef __attribute__((ext_vector_type(16))) float  f32x16;
typedef unsigned short ushort_t;

__device__ __forceinline__ ushort_t f2bf(float f) {
    union { float f; unsigned u; } x; x.f = f;
    unsigned r = x.u + 0x7FFFu + ((x.u >> 16) & 1u);
    return (ushort_t)(r >> 16);
}

// async global->LDS, 16B per lane; lds ptr must be wave-uniform (HW adds lane*16)
__device__ __forceinline__ void gload_lds16(const void* g, void* l) {
    __builtin_amdgcn_global_load_lds((const __attribute__((address_space(1))) void*)g,
                                     (__attribute__((address_space(3))) void*)l, 16, 0, 0);
}

// ---------------------------------------------------------------------------
// rank: ids_shuffle (ws) + ids_restore -> target (f32, d_out tail)
// ---------------------------------------------------------------------------
__global__ void rank_kernel(const float* __restrict__ noise,
                            int* __restrict__ ids_shuffle,
                            float* __restrict__ target_out) {
    int n = blockIdx.x * 256 + threadIdx.x;
    if (n >= BATCH) return;
    float v[NPATCH];
#pragma unroll
    for (int i = 0; i < NPATCH; i++) v[i] = noise[n * NPATCH + i];
#pragma unroll
    for (int j = 0; j < NPATCH; j++) {
        int r = 0;
#pragma unroll
        for (int i = 0; i < NPATCH; i++)
            if (v[i] < v[j] || (v[i] == v[j] && i < j)) r++;
        ids_shuffle[n * NPATCH + r] = j;
        target_out[n * NPATCH + j] = (float)r;
    }
}

// ---------------------------------------------------------------------------
// patch-shuffle + NCHW -> CHWN transpose, f32 in -> bf16 out
// ---------------------------------------------------------------------------
__global__ void shuffle_transpose(const float* __restrict__ x,
                                  const int* __restrict__ ids,
                                  ushort_t* __restrict__ y) {
    __shared__ float tile[64][33];
    int ch = blockIdx.x;           // c*32 + h
    int h = ch & 31;
    int c = ch >> 5;
    int n0 = blockIdx.y << 6;
    int t = threadIdx.x;
    int w = t & 31;
    int jrow = (h >> 3) << 2;
#pragma unroll
    for (int r = 0; r < 8; r++) {
        int nl = (t >> 5) + (r << 3);
        int n = n0 + nl;
        int j = jrow + (w >> 3);
        int p = ids[(n << 4) + j];
        int sh = ((p >> 2) << 3) | (h & 7);
        int sw = ((p & 3) << 3) | (w & 7);
        tile[nl][w] = x[n * 3072 + (c << 10) + (sh << 5) + sw];
    }
    __syncthreads();
#pragma unroll
    for (int r = 0; r < 8; r++) {
        int wo = (t >> 6) + (r << 2);
        int nl = t & 63;
        y[((size_t)(ch << 5) + wo) * 4096 + n0 + nl] = f2bf(tile[nl][wo]);
    }
}

// ---------------------------------------------------------------------------
// conv weight prep: OIHW f32 -> [oc][tap*IC+ic] bf16 (k = tap*IC+ic, zero-pad)
// ---------------------------------------------------------------------------
__global__ void prep_convw(const float* __restrict__ W, ushort_t* __restrict__ WT,
                           int OC, int IC, int KP) {
    int i = blockIdx.x * 256 + threadIdx.x;
    if (i >= OC * KP) return;
    int oc = i / KP, kk = i % KP;
    ushort_t v = 0;
    if (kk < 9 * IC) {
        int tap = kk / IC, ic = kk % IC;
        v = f2bf(W[(oc * IC + ic) * 9 + tap]);
    }
    WT[i] = v;
}

// ---------------------------------------------------------------------------
// FC weight prep: [K][N] f32 -> [N][K] bf16 (LDS-tiled transpose)
// ---------------------------------------------------------------------------
__global__ void transpose_w(const float* __restrict__ W, ushort_t* __restrict__ WT,
                            int K, int N) {
    __shared__ ushort_t t[32][33];
    int kb = blockIdx.x * 32, nb = blockIdx.y * 32;
    int tx = threadIdx.x & 31, ty = threadIdx.x >> 5;   // ty 0..7
#pragma unroll
    for (int i = 0; i < 32; i += 8)
        t[ty + i][tx] = f2bf(W[(size_t)(kb + ty + i) * N + nb + tx]);
    __syncthreads();
#pragma unroll
    for (int i = 0; i < 32; i += 8)
        WT[(size_t)(nb + ty + i) * K + kb + tx] = t[tx][ty + i];
}

// ---------------------------------------------------------------------------
// Implicit-GEMM conv + relu + maxpool2 via mfma_f32_32x32x16_bf16.
// X: CHWN bf16 [IC][H][H][4096]. WT: [OC][KP] bf16 (k = tap*IC+ic).
// Per wave: 32 oc x 32 n, 4 conv positions (2x2 pool window), K-loop in 16s.
// A/B built with the SAME slot->k map (slot (chunk=lane>>5, e) := chunk*8+e),
// so the HW k-interpretation cancels; C/D uses the verified 32x32 mapping.
// FC_EPI: write [n][2048] row-major (fc1 A-layout) instead of CHWN.
// ---------------------------------------------------------------------------
template <int IC, int OC, int H, bool FC_EPI>
__global__ __launch_bounds__(256, 2)
void conv_mfma(const ushort_t* __restrict__ X, const ushort_t* __restrict__ WT,
               const float* __restrict__ bias, ushort_t* __restrict__ Y) {
    constexpr int PH = H / 2;
    constexpr int K  = 9 * IC;
    constexpr int KP = (K + 31) & ~31;
    constexpr int NS = KP / 16;
    const int tid  = threadIdx.x;
    const int wid  = tid >> 6, lane = tid & 63;
    const int nl   = lane & 31;          // n (B col) / oc (A row) lane index
    const int kc   = lane >> 5;          // k-chunk 0/1
    const int pos  = blockIdx.x;
    const int ph   = pos / PH, pw = pos % PH;
    const int ocg  = blockIdx.y;
    const int n0   = (blockIdx.z * 4 + wid) * 32;

    const ushort_t* wp = WT + (size_t)(ocg * 32 + nl) * KP + kc * 8;

    f32x16 acc[4];
#pragma unroll
    for (int p = 0; p < 4; ++p)
#pragma unroll
        for (int r = 0; r < 16; ++r) acc[p][r] = 0.f;

#pragma unroll 2
    for (int s = 0; s < NS; ++s) {
        short8 af = *(const short8*)(wp + s * 16);
#pragma unroll
        for (int p = 0; p < 4; ++p) {
            const int pr = p >> 1, pc = p & 1;
            short8 bf;
            if (IC >= 16) {
                // tap constant within a k-step (16 | IC)
                int tap = (s * 16) / IC;
                int kh = tap / 3, kw = tap % 3;
                int icb = s * 16 - tap * IC;
                int ih = 2 * ph - 1 + pr + kh;
                int iw = 2 * pw - 1 + pc + kw;
                if (ih >= 0 && ih < H && iw >= 0 && iw < H) {
                    const ushort_t* bp = X + (size_t)((icb * H + ih) * H + iw) * 4096
                                           + n0 + nl + (size_t)kc * 8 * H * H * 4096;
#pragma unroll
                    for (int e = 0; e < 8; ++e)
                        bf[e] = (short)bp[(size_t)e * H * H * 4096];
                } else {
#pragma unroll
                    for (int e = 0; e < 8; ++e) bf[e] = 0;
                }
            } else {  // IC == 3 (conv1): per-element tap, masked
#pragma unroll
                for (int e = 0; e < 8; ++e) {
                    int kk = s * 16 + kc * 8 + e;
                    int tap = kk / IC, ic = kk - tap * IC;
                    int kh = tap / 3, kw = tap - kh * 3;
                    int ih = 2 * ph - 1 + pr + kh;
                    int iw = 2 * pw - 1 + pc + kw;
                    bool ok = (kk < K) && ((unsigned)ih < (unsigned)H) && ((unsigned)iw < (unsigned)H);
                    bf[e] = ok ? (short)X[(size_t)((ic * H + ih) * H + iw) * 4096 + n0 + nl]
                               : (short)0;
                }
            }
            acc[p] = __builtin_amdgcn_mfma_f32_32x32x16_bf16(af, bf, acc[p], 0, 0, 0);
        }
    }

    // pool(max4) + bias + relu; C/D: col=lane&31 (=n), row=(reg&3)+4*(lane>>5)+8*(reg>>2)
#pragma unroll
    for (int reg = 0; reg < 16; ++reg) {
        float mx = fmaxf(fmaxf(acc[0][reg], acc[1][reg]), fmaxf(acc[2][reg], acc[3][reg]));
        int ocl = (reg & 3) + 4 * kc + 8 * (reg >> 2);
        int oc  = ocg * 32 + ocl;
        float v = fmaxf(mx + bias[oc], 0.f);
        ushort_t b = f2bf(v);
        if (FC_EPI)
            Y[(size_t)(n0 + nl) * 2048 + oc * 16 + ph * 4 + pw] = b;
        else
            Y[(size_t)((oc * PH + ph) * PH + pw) * 4096 + n0 + nl] = b;
    }
}

// ---------------------------------------------------------------------------
// FC GEMM: C[M][N] = act(A[M][K] @ W + b), weights pre-transposed BT[N][K].
// 128x128 tile, BK=64, 4 waves (2x2), mfma_f32_16x16x32_bf16,
// global_load_lds staging with stage_rc XOR swizzle (chunk c at slot c^(m&7)).
// ---------------------------------------------------------------------------
template <bool RELU, bool F32OUT>
__global__ __launch_bounds__(256, 2)
void fc_mfma(const ushort_t* __restrict__ A, const ushort_t* __restrict__ BT,
             const float* __restrict__ bias, void* __restrict__ Cout,
             int M, int N, int K) {
    __shared__ ushort_t As[128 * 64];
    __shared__ ushort_t Bs[128 * 64];
    const int tid = threadIdx.x;
    const int wid = tid >> 6, lane = tid & 63;
    const int wr = wid >> 1, wc = wid & 1;
    const int tm = blockIdx.y * 128, tn = blockIdx.x * 128;
    const int l15 = lane & 15, l4 = lane >> 4;

    f32x4 acc[4][4];
#pragma unroll
    for (int i = 0; i < 4; ++i)
#pragma unroll
        for (int j = 0; j < 4; ++j)
#pragma unroll
            for (int r = 0; r < 4; ++r) acc[i][j][r] = 0.f;

    for (int k0 = 0; k0 < K; k0 += 64) {
        __syncthreads();   // previous iter's LDS reads done before overwrite
#pragma unroll
        for (int pass = 0; pass < 4; ++pass) {
            int idx = pass * 256 + tid;
            int m = idx >> 3, ss = idx & 7;
            int cc = ss ^ (m & 7);     // slot ss holds chunk cc (involution)
            gload_lds16(A  + (size_t)(tm + m) * K + k0 + cc * 8,
                        &As[(pass * 256 + wid * 64) * 8]);
            gload_lds16(BT + (size_t)(tn + m) * K + k0 + cc * 8,
                        &Bs[(pass * 256 + wid * 64) * 8]);
        }
        __syncthreads();
#pragma unroll
        for (int kk = 0; kk < 2; ++kk) {
            short8 af[4], bfr[4];
            int c = kk * 4 + l4;
#pragma unroll
            for (int i = 0; i < 4; ++i) {
                int m = wr * 64 + i * 16 + l15;
                af[i]  = *(const short8*)(As + m * 64 + (c ^ (m & 7)) * 8);
                int n = wc * 64 + i * 16 + l15;
                bfr[i] = *(const short8*)(Bs + n * 64 + (c ^ (n & 7)) * 8);
            }
#pragma unroll
            for (int i = 0; i < 4; ++i)
#pragma unroll
                for (int j = 0; j < 4; ++j)
                    acc[i][j] = __builtin_amdgcn_mfma_f32_16x16x32_bf16(
                        af[i], bfr[j], acc[i][j], 0, 0, 0);
        }
    }

    // C/D 16x16: col = lane&15, row = (lane>>4)*4 + reg
#pragma unroll
    for (int i = 0; i < 4; ++i) {
        int row = tm + wr * 64 + i * 16 + l4 * 4;
#pragma unroll
        for (int j = 0; j < 4; ++j) {
            int col = tn + wc * 64 + j * 16 + l15;
            float bv = bias[col];
#pragma unroll
            for (int r = 0; r < 4; ++r) {
                float v = acc[i][j][r] + bv;
                if (RELU) v = fmaxf(v, 0.f);
                if (F32OUT)
                    ((float*)Cout)[(size_t)(row + r) * N + col] = v;
                else
                    ((ushort_t*)Cout)[(size_t)(row + r) * N + col] = f2bf(v);
            }
        }
    }
}

// ---------------------------------------------------------------------------
extern "C" void kernel_launch(void* const* d_in, const int* in_sizes, int n_in,
                              void* d_out, int out_size, void* d_ws, size_t ws_size,
                              hipStream_t stream) {
    const float* x     = (const float*)d_in[0];
    const float* noise = (const float*)d_in[1];
    const float* c1w = (const float*)d_in[2];  const float* c1b = (const float*)d_in[3];
    const float* c2w = (const float*)d_in[4];  const float* c2b = (const float*)d_in[5];
    const float* c3w = (const float*)d_in[6];  const float* c3b = (const float*)d_in[7];
    const float* f1w = (const float*)d_in[8];  const float* f1b = (const float*)d_in[9];
    const float* f2w = (const float*)d_in[10]; const float* f2b = (const float*)d_in[11];
    const float* f3w = (const float*)d_in[12]; const float* f3b = (const float*)d_in[13];
    const float* f4w = (const float*)d_in[14]; const float* f4b = (const float*)d_in[15];
    const float* f5w = (const float*)d_in[16]; const float* f5b = (const float*)d_in[17];
    float* out = (float*)d_out;

    char* ws = (char*)d_ws;
    const size_t MB = 1ull << 20;
    int*      ids  = (int*)ws;                       // 256 KB
    ushort_t* wc1  = (ushort_t*)(ws + 1 * MB);       // 2 KB
    ushort_t* wc2  = (ushort_t*)(ws + 1 * MB + 64 * 1024);   // 36 KB
    ushort_t* wc3  = (ushort_t*)(ws + 1 * MB + 128 * 1024);  // 144 KB
    ushort_t* wf1  = (ushort_t*)(ws + 2 * MB);       // 4 MB
    ushort_t* wf2  = (ushort_t*)(ws + 6 * MB);       // 2 MB
    ushort_t* wf3  = (ushort_t*)(ws + 8 * MB);       // 2 MB
    ushort_t* wf4  = (ushort_t*)(ws + 10 * MB);      // 2 MB
    ushort_t* wf5  = (ushort_t*)(ws + 12 * MB);      // 0.5 MB
    ushort_t* act0 = (ushort_t*)(ws + 13 * MB);      // 24 MB  [3][32][32][4096]
    ushort_t* act1 = (ushort_t*)(ws + 37 * MB);      // 64 MB  [32][16][16][4096]
    ushort_t* act2 = (ushort_t*)(ws + 101 * MB);     // 32 MB  [64][8][8][4096]
    ushort_t* act3 = (ushort_t*)(ws + 133 * MB);     // 16 MB  [4096][2048]
    ushort_t* fcb1 = (ushort_t*)(ws + 149 * MB);     // 8 MB   [4096][1024]
    ushort_t* fcb2 = (ushort_t*)(ws + 157 * MB);     // 8 MB

    // weight preps
    prep_convw<<<dim3((32 * 32 + 255) / 256), 256, 0, stream>>>(c1w, wc1, 32, 3, 32);
    prep_convw<<<dim3((64 * 288 + 255) / 256), 256, 0, stream>>>(c2w, wc2, 64, 32, 288);
    prep_convw<<<dim3((128 * 576 + 255) / 256), 256, 0, stream>>>(c3w, wc3, 128, 64, 576);
    transpose_w<<<dim3(64, 32), 256, 0, stream>>>(f1w, wf1, 2048, 1024);
    transpose_w<<<dim3(32, 32), 256, 0, stream>>>(f2w, wf2, 1024, 1024);
    transpose_w<<<dim3(32, 32), 256, 0, stream>>>(f3w, wf3, 1024, 1024);
    transpose_w<<<dim3(32, 32), 256, 0, stream>>>(f4w, wf4, 1024, 1024);
    transpose_w<<<dim3(32, 8),  256, 0, stream>>>(f5w, wf5, 1024, 256);

    // shuffle + target
    rank_kernel<<<BATCH / 256, 256, 0, stream>>>(noise, ids, out + (size_t)BATCH * 256);
    shuffle_transpose<<<dim3(96, 64), 256, 0, stream>>>(x, ids, act0);

    // convs (MFMA implicit GEMM, fused relu+pool)
    conv_mfma<3, 32, 32, false><<<dim3(256, 1, 32), 256, 0, stream>>>(act0, wc1, c1b, act1);
    conv_mfma<32, 64, 16, false><<<dim3(64, 2, 32), 256, 0, stream>>>(act1, wc2, c2b, act2);
    conv_mfma<64, 128, 8, true ><<<dim3(16, 4, 32), 256, 0, stream>>>(act2, wc3, c3b, act3);

    // FC chain (MFMA GEMM)
    fc_mfma<true,  false><<<dim3(8, 32), 256, 0, stream>>>(act3, wf1, f1b, fcb1, BATCH, 1024, 2048);
    fc_mfma<true,  false><<<dim3(8, 32), 256, 0, stream>>>(fcb1, wf2, f2b, fcb2, BATCH, 1024, 1024);
    fc_mfma<true,  false><<<dim3(8, 32), 256, 0, stream>>>(fcb2, wf3, f3b, fcb1, BATCH, 1024, 1024);
    fc_mfma<true,  false><<<dim3(8, 32), 256, 0, stream>>>(fcb1, wf4, f4b, fcb2, BATCH, 1024, 1024);
    fc_mfma<false, true ><<<dim3(2, 32), 256, 0, stream>>>(fcb2, wf5, f5b, out, BATCH, 256, 1024);
}

// Round 6
// 470.963 us; speedup vs baseline: 3.7778x; 1.1352x over previous
//
#include <hip/hip_runtime.h>

#define BATCH 4096
#define NPATCH 16

typedef __attribute__((ext_vector_type(8)))  short  short8;
typedef __attribute__((ext_vector_type(4)))  float  f32x4;
typedef __attribute__((ext_vector_type(16))) float  f32x16;
typedef unsigned short ushort_t;

__device__ __forceinline__ ushort_t f2bf(float f) {
    union { float f; unsigned u; } x; x.f = f;
    unsigned r = x.u + 0x7FFFu + ((x.u >> 16) & 1u);
    return (ushort_t)(r >> 16);
}

__device__ __forceinline__ void gload_lds16(const void* g, void* l) {
    __builtin_amdgcn_global_load_lds((const __attribute__((address_space(1))) void*)g,
                                     (__attribute__((address_space(3))) void*)l, 16, 0, 0);
}

// ---------------------------------------------------------------------------
// rank: ids_shuffle (ws) + ids_restore -> target (f32, d_out tail)
// ---------------------------------------------------------------------------
__global__ void rank_kernel(const float* __restrict__ noise,
                            int* __restrict__ ids_shuffle,
                            float* __restrict__ target_out) {
    int n = blockIdx.x * 256 + threadIdx.x;
    if (n >= BATCH) return;
    float v[NPATCH];
#pragma unroll
    for (int i = 0; i < NPATCH; i++) v[i] = noise[n * NPATCH + i];
#pragma unroll
    for (int j = 0; j < NPATCH; j++) {
        int r = 0;
#pragma unroll
        for (int i = 0; i < NPATCH; i++)
            if (v[i] < v[j] || (v[i] == v[j] && i < j)) r++;
        ids_shuffle[n * NPATCH + r] = j;
        target_out[n * NPATCH + j] = (float)r;
    }
}

// ---------------------------------------------------------------------------
// patch-shuffle + transpose, f32 NCHW -> bf16 [32h][36wpad][4096n][8icpad]
// (ic 3..7 and w-pad slots zeroed). Block: one h x 64 n.
// ---------------------------------------------------------------------------
__global__ void shuffle_transpose(const float* __restrict__ x,
                                  const int* __restrict__ ids,
                                  ushort_t* __restrict__ y) {
    __shared__ float tile[3][64][33];
    int h = blockIdx.x;
    int n0 = blockIdx.y << 6;
    int t = threadIdx.x;
    int w = t & 31;
    int jrow = (h >> 3) << 2;
#pragma unroll
    for (int r = 0; r < 8; r++) {
        int nl = (t >> 5) + (r << 3);
        int n = n0 + nl;
        int j = jrow + (w >> 3);
        int p = ids[(n << 4) + j];
        int sh = ((p >> 2) << 3) | (h & 7);
        int sw = ((p & 3) << 3) | (w & 7);
#pragma unroll
        for (int c = 0; c < 3; c++)
            tile[c][nl][w] = x[n * 3072 + (c << 10) + (sh << 5) + sw];
    }
    __syncthreads();
    int sub = t >> 6, nl = t & 63;
    int n = n0 + nl;
#pragma unroll
    for (int q = 0; q < 9; q++) {
        int wp = sub * 9 + q;            // 0..35
        int iw = wp - 1;
        ushort_t u[8];
#pragma unroll
        for (int e = 0; e < 8; e++) {
            float v = (e < 3 && iw >= 0 && iw < 32) ? tile[e][nl][iw] : 0.f;
            u[e] = f2bf(v);
        }
        *(uint4*)(y + ((size_t)(h * 36 + wp) * 4096 + n) * 8) = *(const uint4*)u;
    }
}

// ---------------------------------------------------------------------------
// conv weight prep: OIHW f32 -> [oc][k] bf16, k = kh*(KWP*ICP)+kw*ICP+ic,
// zero-padded where kw>=3 or ic>=IC.
// ---------------------------------------------------------------------------
__global__ void prep_convw(const float* __restrict__ W, ushort_t* __restrict__ WT,
                           int OC, int IC, int ICP, int KWP) {
    int KP = 3 * KWP * ICP;
    int i = blockIdx.x * 256 + threadIdx.x;
    if (i >= OC * KP) return;
    int oc = i / KP, k = i % KP;
    int kh = k / (KWP * ICP);
    int kw = (k / ICP) % KWP;
    int ic = k % ICP;
    ushort_t v = 0;
    if (kw < 3 && ic < IC)
        v = f2bf(W[((oc * IC + ic) * 3 + kh) * 3 + kw]);
    WT[i] = v;
}

// ---------------------------------------------------------------------------
// FC weight prep: [K][N] f32 -> [N][K] bf16
// ---------------------------------------------------------------------------
__global__ void transpose_w(const float* __restrict__ W, ushort_t* __restrict__ WT,
                            int K, int N) {
    __shared__ ushort_t t[32][33];
    int kb = blockIdx.x * 32, nb = blockIdx.y * 32;
    int tx = threadIdx.x & 31, ty = threadIdx.x >> 5;
#pragma unroll
    for (int i = 0; i < 32; i += 8)
        t[ty + i][tx] = f2bf(W[(size_t)(kb + ty + i) * N + nb + tx]);
    __syncthreads();
#pragma unroll
    for (int i = 0; i < 32; i += 8)
        WT[(size_t)(nb + ty + i) * K + kb + tx] = t[tx][ty + i];
}

// fc1 weights with permuted k: WT[n][k'] = W[k][n], k' = hw*128+c, k = c*16+hw
__global__ void transpose_w_fc1(const float* __restrict__ W, ushort_t* __restrict__ WT) {
    __shared__ ushort_t t[32][33];
    int kb = blockIdx.x * 32, nb = blockIdx.y * 32;   // kb = k'-tile base
    int hw = kb >> 7, c0 = kb & 127;
    int tx = threadIdx.x & 31, ty = threadIdx.x >> 5;
#pragma unroll
    for (int i = 0; i < 32; i += 8)
        t[ty + i][tx] = f2bf(W[(size_t)((c0 + ty + i) * 16 + hw) * 1024 + nb + tx]);
    __syncthreads();
#pragma unroll
    for (int i = 0; i < 32; i += 8)
        WT[(size_t)(nb + ty + i) * 2048 + kb + tx] = t[tx][ty + i];
}

// ---------------------------------------------------------------------------
// conv1: 3->32, 3x3 SAME + relu + pool, mfma 32x32x16 bf16.
// X: [32][36][4096][8] bf16 (padded). WT: [32oc][96] (k = kh*32+kw*8+ic).
// Out: [16][16][4096][32]. One 16B vector load per B-fragment.
// ---------------------------------------------------------------------------
__global__ __launch_bounds__(256, 2)
void conv1_mfma(const ushort_t* __restrict__ X, const ushort_t* __restrict__ WT,
                const float* __restrict__ bias, ushort_t* __restrict__ Y) {
    const int tid = threadIdx.x;
    const int wid = tid >> 6, lane = tid & 63;
    const int nl = lane & 31, kc = lane >> 5;
    const int pos = blockIdx.x;
    const int ph = pos >> 4, pw = pos & 15;
    const int n = (blockIdx.z * 4 + wid) * 32 + nl;

    f32x16 acc[4];
#pragma unroll
    for (int p = 0; p < 4; ++p)
#pragma unroll
        for (int r = 0; r < 16; ++r) acc[p][r] = 0.f;

    const ushort_t* wp_ = WT + nl * 96 + kc * 8;
#pragma unroll
    for (int s = 0; s < 6; ++s) {
        int kh = s >> 1;
        int kw = ((s & 1) << 1) + kc;
        short8 af = *(const short8*)(wp_ + s * 16);
#pragma unroll
        for (int p = 0; p < 4; ++p) {
            int pr = p >> 1, pc = p & 1;
            int ih = 2 * ph + pr - 1 + kh;
            int wpad = 2 * pw + pc + kw;       // 0..34, always in-bounds
            short8 bf = {};
            if ((unsigned)ih < 32u)
                bf = *(const short8*)(X + ((size_t)(ih * 36 + wpad) * 4096 + n) * 8);
            acc[p] = __builtin_amdgcn_mfma_f32_32x32x16_bf16(af, bf, acc[p], 0, 0, 0);
        }
    }
#pragma unroll
    for (int g = 0; g < 4; ++g) {
        ushort_t u[4];
        int ocb = 8 * g + 4 * kc;
#pragma unroll
        for (int j = 0; j < 4; ++j) {
            int reg = 4 * g + j;
            float mx = fmaxf(fmaxf(acc[0][reg], acc[1][reg]), fmaxf(acc[2][reg], acc[3][reg]));
            u[j] = f2bf(fmaxf(mx + bias[ocb + j], 0.f));
        }
        *(uint2*)(Y + ((size_t)(ph * 16 + pw) * 4096 + n) * 32 + ocb) = *(const uint2*)u;
    }
}

// ---------------------------------------------------------------------------
// conv2/3: implicit GEMM + relu + pool, oc-block 64 (2 A-fragments).
// X: [H][H][4096][IC] bf16. WT: [OC][9*IC] (k = tap*IC+ic).
// FC_EPI: write act3[n][2048] with k' = (ph*4+pw)*128 + oc.
// else:   write [H/2][H/2][4096][OCT].
// ---------------------------------------------------------------------------
template <int IC, int H, int OCT, bool FC_EPI>
__global__ __launch_bounds__(256, 2)
void conv_mfma(const ushort_t* __restrict__ X, const ushort_t* __restrict__ WT,
               const float* __restrict__ bias, ushort_t* __restrict__ Y) {
    constexpr int K = 9 * IC, NS = K / 16, SPT = IC / 16, PW = H / 2;
    const int tid = threadIdx.x;
    const int wid = tid >> 6, lane = tid & 63;
    const int nl = lane & 31, kc = lane >> 5;
    const int pos = blockIdx.x;
    const int ph = pos / PW, pw = pos % PW;
    const int ocg = blockIdx.y;
    const int n = (blockIdx.z * 4 + wid) * 32 + nl;

    f32x16 acc[2][4];
#pragma unroll
    for (int a = 0; a < 2; ++a)
#pragma unroll
        for (int p = 0; p < 4; ++p)
#pragma unroll
            for (int r = 0; r < 16; ++r) acc[a][p][r] = 0.f;

    const ushort_t* wpA = WT + (size_t)(ocg * 64 + nl) * K + kc * 8;
#pragma unroll 2
    for (int s = 0; s < NS; ++s) {
        int tap = s / SPT;
        int icb = (s % SPT) * 16 + kc * 8;
        int kh = tap / 3, kw = tap % 3;
        short8 af0 = *(const short8*)(wpA + s * 16);
        short8 af1 = *(const short8*)(wpA + 32 * K + s * 16);
#pragma unroll
        for (int p = 0; p < 4; ++p) {
            int pr = p >> 1, pc = p & 1;
            int ih = 2 * ph + pr - 1 + kh;
            int iw = 2 * pw + pc - 1 + kw;
            short8 bf = {};
            if ((unsigned)ih < (unsigned)H && (unsigned)iw < (unsigned)H)
                bf = *(const short8*)(X + ((size_t)(ih * H + iw) * 4096 + n) * IC + icb);
            acc[0][p] = __builtin_amdgcn_mfma_f32_32x32x16_bf16(af0, bf, acc[0][p], 0, 0, 0);
            acc[1][p] = __builtin_amdgcn_mfma_f32_32x32x16_bf16(af1, bf, acc[1][p], 0, 0, 0);
        }
    }
#pragma unroll
    for (int a = 0; a < 2; ++a)
#pragma unroll
        for (int g = 0; g < 4; ++g) {
            ushort_t u[4];
            int ocl = a * 32 + 8 * g + 4 * kc;
            int oc  = ocg * 64 + ocl;
#pragma unroll
            for (int j = 0; j < 4; ++j) {
                int reg = 4 * g + j;
                float mx = fmaxf(fmaxf(acc[a][0][reg], acc[a][1][reg]),
                                 fmaxf(acc[a][2][reg], acc[a][3][reg]));
                u[j] = f2bf(fmaxf(mx + bias[oc + j], 0.f));
            }
            if (FC_EPI)
                *(uint2*)(Y + (size_t)n * 2048 + (ph * 4 + pw) * 128 + oc) = *(const uint2*)u;
            else
                *(uint2*)(Y + ((size_t)(ph * PW + pw) * 4096 + n) * OCT + oc) = *(const uint2*)u;
        }
}

// ---------------------------------------------------------------------------
// FC GEMM: C[M][N] = act(A[M][K] @ W + b), BT[N][K]. 128x128 tile, BK=64,
// 4 waves, mfma 16x16x32, global_load_lds + stage_rc XOR swizzle. (round-5)
// ---------------------------------------------------------------------------
template <bool RELU, bool F32OUT>
__global__ __launch_bounds__(256, 2)
void fc_mfma(const ushort_t* __restrict__ A, const ushort_t* __restrict__ BT,
             const float* __restrict__ bias, void* __restrict__ Cout,
             int M, int N, int K) {
    __shared__ ushort_t As[128 * 64];
    __shared__ ushort_t Bs[128 * 64];
    const int tid = threadIdx.x;
    const int wid = tid >> 6, lane = tid & 63;
    const int wr = wid >> 1, wc = wid & 1;
    const int tm = blockIdx.y * 128, tn = blockIdx.x * 128;
    const int l15 = lane & 15, l4 = lane >> 4;

    f32x4 acc[4][4];
#pragma unroll
    for (int i = 0; i < 4; ++i)
#pragma unroll
        for (int j = 0; j < 4; ++j)
#pragma unroll
            for (int r = 0; r < 4; ++r) acc[i][j][r] = 0.f;

    for (int k0 = 0; k0 < K; k0 += 64) {
        __syncthreads();
#pragma unroll
        for (int pass = 0; pass < 4; ++pass) {
            int idx = pass * 256 + tid;
            int m = idx >> 3, ss = idx & 7;
            int cc = ss ^ (m & 7);
            gload_lds16(A  + (size_t)(tm + m) * K + k0 + cc * 8,
                        &As[(pass * 256 + wid * 64) * 8]);
            gload_lds16(BT + (size_t)(tn + m) * K + k0 + cc * 8,
                        &Bs[(pass * 256 + wid * 64) * 8]);
        }
        __syncthreads();
#pragma unroll
        for (int kk = 0; kk < 2; ++kk) {
            short8 af[4], bfr[4];
            int c = kk * 4 + l4;
#pragma unroll
            for (int i = 0; i < 4; ++i) {
                int m = wr * 64 + i * 16 + l15;
                af[i]  = *(const short8*)(As + m * 64 + (c ^ (m & 7)) * 8);
                int nn = wc * 64 + i * 16 + l15;
                bfr[i] = *(const short8*)(Bs + nn * 64 + (c ^ (nn & 7)) * 8);
            }
#pragma unroll
            for (int i = 0; i < 4; ++i)
#pragma unroll
                for (int j = 0; j < 4; ++j)
                    acc[i][j] = __builtin_amdgcn_mfma_f32_16x16x32_bf16(
                        af[i], bfr[j], acc[i][j], 0, 0, 0);
        }
    }
#pragma unroll
    for (int i = 0; i < 4; ++i) {
        int row = tm + wr * 64 + i * 16 + l4 * 4;
#pragma unroll
        for (int j = 0; j < 4; ++j) {
            int col = tn + wc * 64 + j * 16 + l15;
            float bv = bias[col];
#pragma unroll
            for (int r = 0; r < 4; ++r) {
                float v = acc[i][j][r] + bv;
                if (RELU) v = fmaxf(v, 0.f);
                if (F32OUT)
                    ((float*)Cout)[(size_t)(row + r) * N + col] = v;
                else
                    ((ushort_t*)Cout)[(size_t)(row + r) * N + col] = f2bf(v);
            }
        }
    }
}

// ---------------------------------------------------------------------------
extern "C" void kernel_launch(void* const* d_in, const int* in_sizes, int n_in,
                              void* d_out, int out_size, void* d_ws, size_t ws_size,
                              hipStream_t stream) {
    const float* x     = (const float*)d_in[0];
    const float* noise = (const float*)d_in[1];
    const float* c1w = (const float*)d_in[2];  const float* c1b = (const float*)d_in[3];
    const float* c2w = (const float*)d_in[4];  const float* c2b = (const float*)d_in[5];
    const float* c3w = (const float*)d_in[6];  const float* c3b = (const float*)d_in[7];
    const float* f1w = (const float*)d_in[8];  const float* f1b = (const float*)d_in[9];
    const float* f2w = (const float*)d_in[10]; const float* f2b = (const float*)d_in[11];
    const float* f3w = (const float*)d_in[12]; const float* f3b = (const float*)d_in[13];
    const float* f4w = (const float*)d_in[14]; const float* f4b = (const float*)d_in[15];
    const float* f5w = (const float*)d_in[16]; const float* f5b = (const float*)d_in[17];
    float* out = (float*)d_out;

    char* ws = (char*)d_ws;
    const size_t MB = 1ull << 20;
    int*      ids  = (int*)ws;                               // 256 KB
    ushort_t* wc1  = (ushort_t*)(ws + 1 * MB);               // 6 KB
    ushort_t* wc2  = (ushort_t*)(ws + 1 * MB + 64 * 1024);   // 36 KB
    ushort_t* wc3  = (ushort_t*)(ws + 1 * MB + 128 * 1024);  // 144 KB
    ushort_t* wf1  = (ushort_t*)(ws + 2 * MB);               // 4 MB
    ushort_t* wf2  = (ushort_t*)(ws + 6 * MB);               // 2 MB
    ushort_t* wf3  = (ushort_t*)(ws + 8 * MB);               // 2 MB
    ushort_t* wf4  = (ushort_t*)(ws + 10 * MB);              // 2 MB
    ushort_t* wf5  = (ushort_t*)(ws + 12 * MB);              // 0.5 MB
    ushort_t* act0 = (ushort_t*)(ws + 13 * MB);              // 75.5 MB [32][36][4096][8]
    ushort_t* act1 = (ushort_t*)(ws + 89 * MB);              // 64 MB  [16][16][4096][32]
    ushort_t* act2 = (ushort_t*)(ws + 153 * MB);             // 32 MB  [8][8][4096][64]
    ushort_t* act3 = (ushort_t*)(ws + 185 * MB);             // 16 MB  [4096][2048]
    ushort_t* fcb1 = (ushort_t*)(ws + 201 * MB);             // 8 MB
    ushort_t* fcb2 = (ushort_t*)(ws + 209 * MB);             // 8 MB

    // weight preps
    prep_convw<<<(32 * 96 + 255) / 256, 256, 0, stream>>>(c1w, wc1, 32, 3, 8, 4);
    prep_convw<<<(64 * 288 + 255) / 256, 256, 0, stream>>>(c2w, wc2, 64, 32, 32, 3);
    prep_convw<<<(128 * 576 + 255) / 256, 256, 0, stream>>>(c3w, wc3, 128, 64, 64, 3);
    transpose_w_fc1<<<dim3(64, 32), 256, 0, stream>>>(f1w, wf1);
    transpose_w<<<dim3(32, 32), 256, 0, stream>>>(f2w, wf2, 1024, 1024);
    transpose_w<<<dim3(32, 32), 256, 0, stream>>>(f3w, wf3, 1024, 1024);
    transpose_w<<<dim3(32, 32), 256, 0, stream>>>(f4w, wf4, 1024, 1024);
    transpose_w<<<dim3(32, 8),  256, 0, stream>>>(f5w, wf5, 1024, 256);

    // shuffle + target
    rank_kernel<<<BATCH / 256, 256, 0, stream>>>(noise, ids, out + (size_t)BATCH * 256);
    shuffle_transpose<<<dim3(32, 64), 256, 0, stream>>>(x, ids, act0);

    // convs (channel-innermost implicit GEMM, fused relu+pool)
    conv1_mfma<<<dim3(256, 1, 32), 256, 0, stream>>>(act0, wc1, c1b, act1);
    conv_mfma<32, 16, 64,  false><<<dim3(64, 1, 32), 256, 0, stream>>>(act1, wc2, c2b, act2);
    conv_mfma<64, 8,  128, true ><<<dim3(16, 2, 32), 256, 0, stream>>>(act2, wc3, c3b, act3);

    // FC chain
    fc_mfma<true,  false><<<dim3(8, 32), 256, 0, stream>>>(act3, wf1, f1b, fcb1, BATCH, 1024, 2048);
    fc_mfma<true,  false><<<dim3(8, 32), 256, 0, stream>>>(fcb1, wf2, f2b, fcb2, BATCH, 1024, 1024);
    fc_mfma<true,  false><<<dim3(8, 32), 256, 0, stream>>>(fcb2, wf3, f3b, fcb1, BATCH, 1024, 1024);
    fc_mfma<true,  false><<<dim3(8, 32), 256, 0, stream>>>(fcb1, wf4, f4b, fcb2, BATCH, 1024, 1024);
    fc_mfma<false, true ><<<dim3(2, 32), 256, 0, stream>>>(fcb2, wf5, f5b, out, BATCH, 256, 1024);
}